// Round 18
// baseline (267.135 us; speedup 1.0000x reference)
//
#include <hip/hip_runtime.h>
#include <cstddef>

#define BB   8
#define NN   2048
#define CIN  64
#define COUT 64
#define KK   20
#define KSS  20
#define C2   128   // 2*CIN
#define PPB  4                 // points per block (4 waves of 64)
#define NC   24                // fp32 candidate count for knn refine
#define KT   80                // K-steps of 32 in conv (2560/32)
#define AGG_LD 2576            // padded agg row (f16)

#define PREP_NB 80             // front_kernel block ranges
#define TR_NB   256
#define KNN_NB  (BB * NN / 4)  // 4096

// EMPIRICAL launch_bounds rule on this toolchain (measured r0-r17):
// VGPR cap ~= 256/arg for 256-thread blocks: (256,3)->84, (256,4)->64,
// (256,8)->32; (512,4)->64, (512,2)->~128. Caps below demand => scratch
// spill (r2: 440MB, r9: 370MB). Keep demand < cap.
// FALSIFIED experiments (do not retry):
//  r8  pk2/uint2 agg stores + float4 finalize: +15 µs (spill)
//  r11 knn at 64-reg cap: null (knn not residency-bound)
//  r16 float2 packed agg + fg-hoist: +4 µs (latency-chain-bound, not issue)
// r17 = r12 best body re-measured: 235.9 µs total, point 111.2 µs.
// r18 change: bn_reduce FUSED into point_kernel finalize (atomicAdd of
// per-block channel partials into part2; agg_h LDS reused post-barrier-2).
// Eliminates one dispatch + an 8.4 MB re-read of `out`.

typedef _Float16 h2t  __attribute__((ext_vector_type(2)));
typedef _Float16 f16x8 __attribute__((ext_vector_type(8)));
typedef float    f32x4 __attribute__((ext_vector_type(4)));

__device__ __forceinline__ unsigned pk2(float a, float b) {
    unsigned short ua = __builtin_bit_cast(unsigned short, (_Float16)a);
    unsigned short ub = __builtin_bit_cast(unsigned short, (_Float16)b);
    return (unsigned)ua | ((unsigned)ub << 16);
}

// Wave64 min-reduce on the VALU via DPP (row_shr into HIGH lane of each
// 16-row; bcast15/31 merge; lane 63 = global min). Verified r6.
__device__ __forceinline__ unsigned wave_min_u32(unsigned v) {
    unsigned x = v, t;
    t = (unsigned)__builtin_amdgcn_update_dpp((int)x, (int)x, 0x111, 0xf, 0xf, false);
    x = (t < x) ? t : x;
    t = (unsigned)__builtin_amdgcn_update_dpp((int)x, (int)x, 0x112, 0xf, 0xf, false);
    x = (t < x) ? t : x;
    t = (unsigned)__builtin_amdgcn_update_dpp((int)x, (int)x, 0x114, 0xf, 0xf, false);
    x = (t < x) ? t : x;
    t = (unsigned)__builtin_amdgcn_update_dpp((int)x, (int)x, 0x118, 0xf, 0xf, false);
    x = (t < x) ? t : x;
    t = (unsigned)__builtin_amdgcn_update_dpp((int)x, (int)x, 0x142, 0xf, 0xf, false);
    x = (t < x) ? t : x;
    t = (unsigned)__builtin_amdgcn_update_dpp((int)x, (int)x, 0x143, 0xf, 0xf, false);
    x = (t < x) ? t : x;
    return (unsigned)__builtin_amdgcn_readlane((int)x, 63);
}

// identical expression everywhere -> identical rounding (self-consistency
// between build, radix counts, and fallback rescan).
__device__ __forceinline__ float d2f(float px, float py, float pz,
                                     float qx, float qy, float qz) {
    float dx = px - qx, dy = py - qy, dz = pz - qz;
    return fmaf(dz, dz, fmaf(dy, dy, dx * dx));
}

__device__ __forceinline__ unsigned long long umin64(unsigned long long a,
                                                     unsigned long long b) {
    return a < b ? a : b;
}
__device__ __forceinline__ unsigned long long umax64(unsigned long long a,
                                                     unsigned long long b) {
    return a < b ? b : a;
}

// insert pk into the sorted ascending 4-tuple (c0<=c1<=c2<=c3)
#define INS4(c0, c1, c2, c3, pk) do { \
    if (pk < c0)      { c3 = c2; c2 = c1; c1 = c0; c0 = pk; } \
    else if (pk < c1) { c3 = c2; c2 = c1; c1 = pk; } \
    else if (pk < c2) { c3 = c2; c2 = pk; } \
    else if (pk < c3) { c3 = pk; } \
} while (0)

// EXACT top-4 of two sorted ascending 4-tuples (selection identity:
// k-th smallest of union = min(a_k, b_k, min_{i+j=k-1} max(a_i,b_j))).
#define MERGE4(r0, r1, r2, r3, a0, a1, a2, a3, b0, b1, b2, b3) do { \
    r0 = umin64(a0, b0); \
    r1 = umin64(umin64(a1, b1), umax64(a0, b0)); \
    r2 = umin64(umin64(a2, b2), umin64(umax64(a0, b1), umax64(a1, b0))); \
    r3 = umin64(umin64(a3, b3), \
         umin64(umax64(a0, b2), umin64(umax64(a1, b1), umax64(a2, b0)))); \
} while (0)

// ---------------------------------------------------------------------------
// FRONT kernel: prep + featT-transpose + KNN fused (r12 structure).
// ---------------------------------------------------------------------------
__global__ __launch_bounds__(256, 3) void front_kernel(
    const float* __restrict__ cw, const float* __restrict__ mw,
    uint4* __restrict__ aFrag, float* __restrict__ mowT,
    const float* __restrict__ f, float* __restrict__ ft,
    const float* __restrict__ x, int* __restrict__ nid)
{
    __shared__ float tile[64][65];     // tr path
    __shared__ int cand_s[4][32];      // knn path

    const int blk = blockIdx.x;
    const int tid = threadIdx.x;

    if (blk < PREP_NB) {
        // ---------------- prep path ----------------
        int i = blk * 256 + tid;
        if (i < 4 * KT * 64) {
            int wv = i / (KT * 64);
            int r  = i - wv * (KT * 64);
            int t  = r >> 6, l = r & 63;
            int o  = (wv << 4) + (l & 15);
            int j  = (t << 5) + ((l >> 4) << 3);
            const float* s = cw + (size_t)o * (C2 * KSS) + j;
            uint4 v;
            v.x = pk2(s[0], s[1]);
            v.y = pk2(s[2], s[3]);
            v.z = pk2(s[4], s[5]);
            v.w = pk2(s[6], s[7]);
            aFrag[i] = v;
        }
        if (i < COUT * CIN) {
            int o = i >> 6, c = i & 63;
            mowT[c * COUT + o] = mw[o * CIN + c];
        }
        return;
    }

    if (blk < PREP_NB + TR_NB) {
        // ---------------- transpose path ----------------
        const int bt = blk - PREP_NB;      // b*32 + ntile
        const int b  = bt >> 5;
        const int n0 = (bt & 31) << 6;
        const int tn  = tid & 63;
        const int tc0 = tid >> 6;          // 0..3
#pragma unroll
        for (int r = 0; r < 16; ++r) {
            int c = (r << 2) + tc0;
            tile[c][tn] = f[((size_t)(b * CIN + c)) * NN + n0 + tn];
        }
        __syncthreads();
#pragma unroll
        for (int r = 0; r < 16; ++r) {
            int n = (r << 2) + tc0;
            ft[((size_t)b * NN + n0 + n) * CIN + tn] = tile[tn][n];
        }
        return;
    }

    // ---------------- KNN path ----------------
    const int w    = tid >> 6;
    const int lane = tid & 63;
    const int p    = (blk - PREP_NB - TR_NB) * 4 + w;
    const int b    = p >> 11;
    const int n    = p & (NN - 1);

    const float* xb0 = x + (size_t)(b * 3 + 0) * NN;
    const float* xb1 = x + (size_t)(b * 3 + 1) * NN;
    const float* xb2 = x + (size_t)(b * 3 + 2) * NN;

    const unsigned long long SENT = 0xFFFFFFFFFFFFFFFFull;
    const float qx = xb0[n], qy = xb1[n], qz = xb2[n];

    // ---- build: 2 independent top-4 chains (halved serial chain) ----
    unsigned long long a0 = SENT, a1 = SENT, a2 = SENT, a3 = SENT;
    unsigned long long e0 = SENT, e1 = SENT, e2 = SENT, e3 = SENT;
#pragma unroll
    for (int jj = 0; jj < 8; ++jj) {
        const int m0 = jj * 256 + lane * 4;
        const float4 vx = *(const float4*)&xb0[m0];
        const float4 vy = *(const float4*)&xb1[m0];
        const float4 vz = *(const float4*)&xb2[m0];
        const float d0 = d2f(vx.x, vy.x, vz.x, qx, qy, qz);
        const float d1 = d2f(vx.y, vy.y, vz.y, qx, qy, qz);
        const float d2 = d2f(vx.z, vy.z, vz.z, qx, qy, qz);
        const float d3 = d2f(vx.w, vy.w, vz.w, qx, qy, qz);
        unsigned long long pk0 =
            ((unsigned long long)__float_as_uint(d0) << 32) | (unsigned)(m0 + 0);
        unsigned long long pk1 =
            ((unsigned long long)__float_as_uint(d1) << 32) | (unsigned)(m0 + 1);
        unsigned long long pk2_ =
            ((unsigned long long)__float_as_uint(d2) << 32) | (unsigned)(m0 + 2);
        unsigned long long pk3 =
            ((unsigned long long)__float_as_uint(d3) << 32) | (unsigned)(m0 + 3);
        INS4(a0, a1, a2, a3, pk0);
        INS4(a0, a1, a2, a3, pk1);
        INS4(e0, e1, e2, e3, pk2_);
        INS4(e0, e1, e2, e3, pk3);
    }
    unsigned long long c0, c1, c2, c3;
    MERGE4(c0, c1, c2, c3, a0, a1, a2, a3, e0, e1, e2, e3);

    const unsigned dv0 = (unsigned)(c0 >> 32), dv1 = (unsigned)(c1 >> 32);
    const unsigned dv2 = (unsigned)(c2 >> 32), dv3 = (unsigned)(c3 >> 32);

    // ---- radix select: tau = 24th smallest d2bits over 256 cached keys ----
    unsigned pfx = 0u;
    for (int i = 30; i >= 0; --i) {      // bit31 of +float is always 0
        unsigned T = pfx | (1u << i);
        int cnt = (int)(dv0 < T) + (int)(dv1 < T) + (int)(dv2 < T) + (int)(dv3 < T);
        unsigned long long B0 = __ballot(cnt & 1);
        unsigned long long B1 = __ballot(cnt & 2);
        unsigned long long B2 = __ballot(cnt & 4);
        int tot = __popcll(B0) + 2 * __popcll(B1) + 4 * __popcll(B2);
        if (tot < NC) pfx = T;           // kth >= T -> set this bit
    }
    const unsigned tau = pfx;

    // ---- counts at tau; trigger decides fast vs fallback (wave-uniform) ----
    int cle = (int)(dv0 <= tau) + (int)(dv1 <= tau)
            + (int)(dv2 <= tau) + (int)(dv3 <= tau);
    unsigned long long L0 = __ballot(cle & 1);
    unsigned long long L1 = __ballot(cle & 2);
    unsigned long long L2 = __ballot(cle & 4);
    int tot_le = __popcll(L0) + 2 * __popcll(L1) + 4 * __popcll(L2);
    const bool trigger = (tot_le != NC) || (__ballot(cle == 4) != 0ull);

    int ci_cand = 0x7fffffff;
    if (!trigger) {
        // ---- fast path: prefix-compact the <=tau set (exactly 24 keys) ----
        unsigned long long below = (1ull << lane) - 1ull;
        int pre = __popcll(L0 & below) + 2 * __popcll(L1 & below);
        if (cle >= 1) cand_s[w][pre + 0] = (int)(unsigned)c0;
        if (cle >= 2) cand_s[w][pre + 1] = (int)(unsigned)c1;
        if (cle >= 3) cand_s[w][pre + 2] = (int)(unsigned)c2;
        if (lane < NC) ci_cand = cand_s[w][lane];   // wave-local, no barrier
    } else {
        // ---- fallback: sequential DPP extraction; rescan recomputes d2 ----
        unsigned killmask = 0u;
        unsigned long long mypk = SENT;
        for (int k = 0; k < NC; ++k) {
            unsigned myd  = (unsigned)(c0 >> 32);
            unsigned dmin = wave_min_u32(myd);
            unsigned idxc = (myd == dmin) ? (unsigned)c0 : 0xFFFFFFFFu;
            unsigned imin = wave_min_u32(idxc);
            unsigned long long bp = ((unsigned long long)dmin << 32) | imin;
            if (lane == k) mypk = bp;
            if (c0 == bp) {                       // unique owner lane
                unsigned mi = (unsigned)(bp & 0xFFFFFFFFull);
                killmask |= 1u << (((mi >> 8) << 2) | (mi & 3));
                c0 = c1; c1 = c2; c2 = c3; c3 = SENT;
                if (c0 == SENT) {                 // rare rescan (recompute)
                    for (int jj = 0; jj < 8; ++jj) {
                        const int m0 = jj * 256 + lane * 4;
                        const float4 vx = *(const float4*)&xb0[m0];
                        const float4 vy = *(const float4*)&xb1[m0];
                        const float4 vz = *(const float4*)&xb2[m0];
                        const float dd4[4] = { d2f(vx.x, vy.x, vz.x, qx, qy, qz),
                                               d2f(vx.y, vy.y, vz.y, qx, qy, qz),
                                               d2f(vx.z, vy.z, vz.z, qx, qy, qz),
                                               d2f(vx.w, vy.w, vz.w, qx, qy, qz) };
#pragma unroll
                        for (int e = 0; e < 4; ++e) {
                            if (killmask & (1u << ((jj << 2) | e))) continue;
                            unsigned long long pk =
                                ((unsigned long long)__float_as_uint(dd4[e]) << 32)
                                | (unsigned)(m0 + e);
                            INS4(c0, c1, c2, c3, pk);
                        }
                    }
                }
            }
        }
        if (lane < NC) ci_cand = (int)(mypk & 0xFFFFFFFFull);
    }

    // ---- double-precision refine + full bitonic sort (order-independent) --
    double dd = 1e300;
    int ci = 0x7fffffff;
    if (lane < NC) {
        ci = ci_cand;
        double dx = (double)xb0[ci] - (double)qx;
        double dy = (double)xb1[ci] - (double)qy;
        double dz = (double)xb2[ci] - (double)qz;
        dd = dx * dx + dy * dy + dz * dz;
    }
    unsigned long long db = __double_as_longlong(dd);
#pragma unroll
    for (int size = 2; size <= 32; size <<= 1) {
#pragma unroll
        for (int stride = size >> 1; stride > 0; stride >>= 1) {
            unsigned long long odb = __shfl_xor(db, stride);
            int oci = __shfl_xor(ci, stride);
            bool up = ((lane & size) == 0);
            bool takemin = (((lane & stride) == 0) == up);
            bool oless = (odb < db) || (odb == db && oci < ci);
            if (takemin == oless) { db = odb; ci = oci; }
        }
    }
    if (lane < KK) nid[(size_t)p * KK + lane] = ci;
}

// ---------------------------------------------------------------------------
// FUSED kernel — r12 best body + r18 BN-stat fusion: after finalize, block
// reduces acc/acc^2 per channel (agg_h LDS reused post-barrier-2) and wave 0
// atomicAdds 128 partials into part2. Replaces bn_reduce's 8.4 MB re-read.
// ---------------------------------------------------------------------------
__global__ __launch_bounds__(256, 3) void point_kernel(
    const float* __restrict__ x,
    const float* __restrict__ featT,
    const float* __restrict__ kern,
    const float* __restrict__ pad,
    const float* __restrict__ mlp_w,
    const float* __restrict__ mlp_b,
    const uint4* __restrict__ aFrag,
    const float* __restrict__ conv_b,
    const float* __restrict__ mowT,
    const float* __restrict__ mob,
    const int* __restrict__ nid,
    float* __restrict__ out,
    float* __restrict__ part2)
{
    __shared__ __align__(16) _Float16 agg_h[PPB][AGG_LD];    // 20608 B
    __shared__ __align__(16) float u_s[PPB * KK * KSS];      // 6400 B (perm|red2)
    __shared__ float xr_s[PPB][KK][3];
    __shared__ float xd_s[PPB][KK];
    __shared__ float xrep_s[PPB][3];
    __shared__ float colden_s[PPB][KSS];
    __shared__ float fcol_s[PPB][CIN];
    __shared__ int   nid_s[PPB][KK];

    float (*perm_s)[KK][KSS] = (float (*)[KK][KSS])u_s;
    float (*red2)[COUT]      = (float (*)[COUT])u_s;   // aliased post-barrier1

    const int tid  = threadIdx.x;
    const int w    = tid >> 6;
    const int lane = tid & 63;
    const int p    = blockIdx.x * PPB + w;
    const int b    = p >> 11;
    const int n    = p & (NN - 1);

    const float* xb0 = x + (size_t)(b * 3 + 0) * NN;
    const float* xb1 = x + (size_t)(b * 3 + 1) * NN;
    const float* xb2 = x + (size_t)(b * 3 + 2) * NN;

    // ---- neighbor ids from the KNN kernel (wave-local LDS stage) ----
    if (lane < KK) nid_s[w][lane] = nid[(size_t)p * KK + lane];

    // ======= per-point pipeline: all wave-local, NO barriers needed =======
    fcol_s[w][lane] = featT[((size_t)b * NN + n) * CIN + lane];

    if (lane == 0) {
        int m0 = nid_s[w][0];
        xrep_s[w][0] = xb0[m0]; xrep_s[w][1] = xb1[m0]; xrep_s[w][2] = xb2[m0];
    }
    if (lane < KK) {
        int m = nid_s[w][lane];
        float rx = xb0[m] - xrep_s[w][0];
        float ry = xb1[m] - xrep_s[w][1];
        float rz = xb2[m] - xrep_s[w][2];
        xr_s[w][lane][0] = rx; xr_s[w][lane][1] = ry; xr_s[w][lane][2] = rz;
        xd_s[w][lane] = sqrtf(rx * rx + ry * ry + rz * rz + 1e-12f);
    }

    // ---- perm: relu -> colnorm -> square -> colnorm -> >0.1 (wave-local) --
    for (int e = lane; e < KK * KSS; e += 64) {
        int k = e / KSS, m = e % KSS;
        float v = xr_s[w][k][0] * kern[0 * KSS + m]
                + xr_s[w][k][1] * kern[1 * KSS + m]
                + xr_s[w][k][2] * kern[2 * KSS + m]
                + pad[k * KSS + m];
        perm_s[w][k][m] = v > 0.0f ? v : 0.0f;
    }
    if (lane < KSS) {
        float s = 0.0f;
        for (int k = 0; k < KK; ++k) s += perm_s[w][k][lane];
        colden_s[w][lane] = s + 1e-6f;
    }
    for (int e = lane; e < KK * KSS; e += 64) {
        int k = e / KSS, m = e % KSS;
        float v = perm_s[w][k][m] / colden_s[w][m];
        perm_s[w][k][m] = v * v;
    }
    if (lane < KSS) {
        float s = 0.0f;
        for (int k = 0; k < KK; ++k) s += perm_s[w][k][lane];
        colden_s[w][lane] = s + 1e-6f;
    }
    for (int e = lane; e < KK * KSS; e += 64) {
        int k = e / KSS, m = e % KSS;
        float v = perm_s[w][k][m] / colden_s[w][m];
        perm_s[w][k][m] = v > 0.1f ? v : 0.0f;
    }

    // ---- feats in registers (coalesced gathers from featT) ----
    float fg[KK], fm[KK];
#pragma unroll
    for (int k = 0; k < KK; ++k)
        fg[k] = featT[((size_t)b * NN + nid_s[w][k]) * CIN + lane];
    {
        float w0 = mlp_w[lane * 7 + 0], w1 = mlp_w[lane * 7 + 1];
        float w2 = mlp_w[lane * 7 + 2], w3 = mlp_w[lane * 7 + 3];
        float w4 = mlp_w[lane * 7 + 4], w5 = mlp_w[lane * 7 + 5];
        float w6 = mlp_w[lane * 7 + 6];
        float bias = mlp_b[lane];
#pragma unroll
        for (int k = 0; k < KK; ++k) {
            fm[k] = xrep_s[w][0] * w0 + xrep_s[w][1] * w1 + xrep_s[w][2] * w2
                  + xr_s[w][k][0] * w3 + xr_s[w][k][1] * w4 + xr_s[w][k][2] * w5
                  + xd_s[w][k] * w6 + bias;
        }
    }

    // ---- agg rows c=lane, c=64+lane; float4 perm reads (broadcast, free) --
#pragma unroll
    for (int m4 = 0; m4 < KSS / 4; ++m4) {
        float sx = 0.f, sy = 0.f, sz = 0.f, sw = 0.f;
        float tx = 0.f, ty = 0.f, tz = 0.f, tw = 0.f;
#pragma unroll
        for (int k = 0; k < KK; ++k) {
            const float4 pv = *(const float4*)&perm_s[w][k][m4 * 4];
            const float a = fg[k], c = fm[k];
            sx += a * pv.x; sy += a * pv.y; sz += a * pv.z; sw += a * pv.w;
            tx += c * pv.x; ty += c * pv.y; tz += c * pv.z; tw += c * pv.w;
        }
        const int mb = m4 * 4;
        agg_h[w][lane * KSS + mb + 0]         = (_Float16)sx;
        agg_h[w][lane * KSS + mb + 1]         = (_Float16)sy;
        agg_h[w][lane * KSS + mb + 2]         = (_Float16)sz;
        agg_h[w][lane * KSS + mb + 3]         = (_Float16)sw;
        agg_h[w][(CIN + lane) * KSS + mb + 0] = (_Float16)tx;
        agg_h[w][(CIN + lane) * KSS + mb + 1] = (_Float16)ty;
        agg_h[w][(CIN + lane) * KSS + mb + 2] = (_Float16)tz;
        agg_h[w][(CIN + lane) * KSS + mb + 3] = (_Float16)tw;
    }
    __syncthreads();   // BARRIER 1: cross-wave agg_h; perm_s -> red2 handoff

    // ---- cooperative conv on the MATRIX pipe: wave w = outputs 16w..16w+15
    {
        f32x4 acc0 = {0.f, 0.f, 0.f, 0.f};
        f32x4 acc1 = {0.f, 0.f, 0.f, 0.f};
        const uint4* ap = aFrag + (size_t)(w * KT) * 64 + lane;
        const _Float16* bp = &agg_h[lane & 3][(lane >> 4) * 8];
#pragma unroll 4
        for (int t = 0; t < KT; t += 2) {
            uint4 av0 = ap[(size_t)t * 64];
            uint4 av1 = ap[(size_t)(t + 1) * 64];
            f16x8 b0 = *(const f16x8*)(bp + t * 32);
            f16x8 b1 = *(const f16x8*)(bp + (t + 1) * 32);
            acc0 = __builtin_amdgcn_mfma_f32_16x16x32_f16(
                       __builtin_bit_cast(f16x8, av0), b0, acc0, 0, 0, 0);
            acc1 = __builtin_amdgcn_mfma_f32_16x16x32_f16(
                       __builtin_bit_cast(f16x8, av1), b1, acc1, 0, 0, 0);
        }
        acc0 += acc1;
        if ((lane & 15) < 4) {
            const int p2 = lane & 15;
            const int ob = (w << 4) + ((lane >> 4) << 2);
            *(f32x4*)&red2[p2][ob] = acc0;
        }
    }
    __syncthreads();   // BARRIER 2: cross-wave red2; agg_h now DEAD

    // ---- wave w finalizes point w; stage BN partials into dead agg_h ----
    {
        float acc = conv_b[lane] + red2[w][lane];
        for (int c = 0; c < CIN; ++c)
            acc += fcol_s[w][c] * mowT[c * COUT + lane];
        acc += mob[lane];
        out[(size_t)(b * COUT + lane) * NN + n] = acc;

        float* ps = (float*)agg_h;               // 512 floats needed; 20KB free
        ps[w * COUT + lane]       = acc;
        ps[256 + w * COUT + lane] = acc * acc;
    }
    __syncthreads();   // BARRIER 3: cross-wave BN partials
    if (w == 0) {
        const float* ps = (const float*)agg_h;
        float s = (ps[lane] + ps[COUT + lane])
                + (ps[2 * COUT + lane] + ps[3 * COUT + lane]);
        float q = (ps[256 + lane] + ps[256 + COUT + lane])
                + (ps[256 + 2 * COUT + lane] + ps[256 + 3 * COUT + lane]);
        atomicAdd(&part2[lane], s);
        atomicAdd(&part2[COUT + lane], q);
    }
}

// ---------------------------------------------------------------------------
// BatchNorm apply: stats come from part2 (accumulated by point_kernel).
// ---------------------------------------------------------------------------
__global__ __launch_bounds__(256) void bn_apply(
    float* __restrict__ out, const float* __restrict__ part2,
    const float* __restrict__ gamma, const float* __restrict__ beta)
{
    const int o = blockIdx.x >> 3;
    const int s = blockIdx.x & 7;
    const float a = part2[o];
    const float q = part2[COUT + o];
    const float M = (float)(BB * NN);
    const float mean = a / M;
    float var = q / M - mean * mean;
    if (var < 0.f) var = 0.f;
    const float inv = 1.0f / sqrtf(var + 1e-5f);
    const float g = gamma[o] * inv, be = beta[o];
    float* dst = out + (size_t)(s * COUT + o) * NN;
    for (int i = threadIdx.x; i < NN; i += 256) {
        dst[i] = (dst[i] - mean) * g + be;
    }
}

// ---------------------------------------------------------------------------
extern "C" void kernel_launch(void* const* d_in, const int* in_sizes, int n_in,
                              void* d_out, int out_size, void* d_ws, size_t ws_size,
                              hipStream_t stream)
{
    const float* x       = (const float*)d_in[0];
    const float* feature = (const float*)d_in[1];
    const float* kern    = (const float*)d_in[2];
    const float* pad     = (const float*)d_in[3];
    const float* mlp_w   = (const float*)d_in[4];
    const float* mlp_b   = (const float*)d_in[5];
    const float* conv_w  = (const float*)d_in[6];
    const float* conv_b  = (const float*)d_in[7];
    const float* mow     = (const float*)d_in[8];
    const float* mob     = (const float*)d_in[9];
    const float* gamma   = (const float*)d_in[10];
    const float* beta    = (const float*)d_in[11];

    char* wsp = (char*)d_ws;
    uint4* aFrag = (uint4*)wsp;                        // 327680 B
    float* mowT  = (float*)(wsp + 327680);             //  16384 B
    float* part2 = (float*)(wsp + 327680 + 16384);     //    512 B (sum|sumsq)
    int*   nid   = (int*)(wsp + 327680 + 16384 + 4096);// 1310720 B
    float* featT = (float*)(wsp + 327680 + 16384 + 4096 + 1310720); // 4 MB

    float* out = (float*)d_out;

    hipMemsetAsync(part2, 0, 2 * COUT * sizeof(float), stream);
    front_kernel<<<PREP_NB + TR_NB + KNN_NB, 256, 0, stream>>>(
        conv_w, mow, aFrag, mowT, feature, featT, x, nid);
    point_kernel<<<BB * NN / PPB, 256, 0, stream>>>(x, featT, kern, pad,
                                                    mlp_w, mlp_b, aFrag, conv_b,
                                                    mowT, mob, nid, out, part2);
    bn_apply<<<512, 256, 0, stream>>>(out, part2, gamma, beta);
}

// Round 19
// 235.580 us; speedup vs baseline: 1.1339x; 1.1339x over previous
//
#include <hip/hip_runtime.h>
#include <cstddef>

#define BB   8
#define NN   2048
#define CIN  64
#define COUT 64
#define KK   20
#define KSS  20
#define C2   128   // 2*CIN
#define PPB  4                 // points per block (4 waves of 64)
#define NC   24                // fp32 candidate count for knn refine
#define KT   80                // K-steps of 32 in conv (2560/32)
#define AGG_LD 2576            // padded agg row (f16)

#define PREP_NB 80             // front_kernel block ranges
#define TR_NB   256
#define KNN_NB  (BB * NN / 4)  // 4096

// EMPIRICAL launch_bounds rule on this toolchain (measured r0-r18):
// VGPR cap ~= 256/arg for 256-thread blocks: (256,3)->84, (256,4)->64,
// (256,8)->32; (512,4)->64, (512,2)->~128. Caps below demand => scratch
// spill (r2: 440MB, r9: 370MB). Keep demand < cap.
// FALSIFIED experiments (do not retry):
//  r8  pk2/uint2 agg stores + float4 finalize: +15 µs (spill)
//  r11 knn at 64-reg cap: null (knn not residency-bound)
//  r16 float2 packed agg + fg-hoist: +4 µs (latency-chain-bound, not issue)
//  r18 BN-stat fusion into point (barrier3 + atomics): +23 µs on point
// This file == r17 measured best: 235.9 µs total (point 111.2, front ~90,
// bn+gaps ~35). Latency-bound local optimum; no pipe near a HW ceiling.

typedef _Float16 h2t  __attribute__((ext_vector_type(2)));
typedef _Float16 f16x8 __attribute__((ext_vector_type(8)));
typedef float    f32x4 __attribute__((ext_vector_type(4)));

__device__ __forceinline__ unsigned pk2(float a, float b) {
    unsigned short ua = __builtin_bit_cast(unsigned short, (_Float16)a);
    unsigned short ub = __builtin_bit_cast(unsigned short, (_Float16)b);
    return (unsigned)ua | ((unsigned)ub << 16);
}

// Wave64 min-reduce on the VALU via DPP (row_shr into HIGH lane of each
// 16-row; bcast15/31 merge; lane 63 = global min). Verified r6.
__device__ __forceinline__ unsigned wave_min_u32(unsigned v) {
    unsigned x = v, t;
    t = (unsigned)__builtin_amdgcn_update_dpp((int)x, (int)x, 0x111, 0xf, 0xf, false);
    x = (t < x) ? t : x;
    t = (unsigned)__builtin_amdgcn_update_dpp((int)x, (int)x, 0x112, 0xf, 0xf, false);
    x = (t < x) ? t : x;
    t = (unsigned)__builtin_amdgcn_update_dpp((int)x, (int)x, 0x114, 0xf, 0xf, false);
    x = (t < x) ? t : x;
    t = (unsigned)__builtin_amdgcn_update_dpp((int)x, (int)x, 0x118, 0xf, 0xf, false);
    x = (t < x) ? t : x;
    t = (unsigned)__builtin_amdgcn_update_dpp((int)x, (int)x, 0x142, 0xf, 0xf, false);
    x = (t < x) ? t : x;
    t = (unsigned)__builtin_amdgcn_update_dpp((int)x, (int)x, 0x143, 0xf, 0xf, false);
    x = (t < x) ? t : x;
    return (unsigned)__builtin_amdgcn_readlane((int)x, 63);
}

// identical expression everywhere -> identical rounding (self-consistency
// between build, radix counts, and fallback rescan).
__device__ __forceinline__ float d2f(float px, float py, float pz,
                                     float qx, float qy, float qz) {
    float dx = px - qx, dy = py - qy, dz = pz - qz;
    return fmaf(dz, dz, fmaf(dy, dy, dx * dx));
}

__device__ __forceinline__ unsigned long long umin64(unsigned long long a,
                                                     unsigned long long b) {
    return a < b ? a : b;
}
__device__ __forceinline__ unsigned long long umax64(unsigned long long a,
                                                     unsigned long long b) {
    return a < b ? b : a;
}

// insert pk into the sorted ascending 4-tuple (c0<=c1<=c2<=c3)
#define INS4(c0, c1, c2, c3, pk) do { \
    if (pk < c0)      { c3 = c2; c2 = c1; c1 = c0; c0 = pk; } \
    else if (pk < c1) { c3 = c2; c2 = c1; c1 = pk; } \
    else if (pk < c2) { c3 = c2; c2 = pk; } \
    else if (pk < c3) { c3 = pk; } \
} while (0)

// EXACT top-4 of two sorted ascending 4-tuples (selection identity:
// k-th smallest of union = min(a_k, b_k, min_{i+j=k-1} max(a_i,b_j))).
#define MERGE4(r0, r1, r2, r3, a0, a1, a2, a3, b0, b1, b2, b3) do { \
    r0 = umin64(a0, b0); \
    r1 = umin64(umin64(a1, b1), umax64(a0, b0)); \
    r2 = umin64(umin64(a2, b2), umin64(umax64(a0, b1), umax64(a1, b0))); \
    r3 = umin64(umin64(a3, b3), \
         umin64(umax64(a0, b2), umin64(umax64(a1, b1), umax64(a2, b0)))); \
} while (0)

// ---------------------------------------------------------------------------
// FRONT kernel: prep + featT-transpose + KNN fused (r12 structure).
// ---------------------------------------------------------------------------
__global__ __launch_bounds__(256, 3) void front_kernel(
    const float* __restrict__ cw, const float* __restrict__ mw,
    uint4* __restrict__ aFrag, float* __restrict__ mowT,
    const float* __restrict__ f, float* __restrict__ ft,
    const float* __restrict__ x, int* __restrict__ nid)
{
    __shared__ float tile[64][65];     // tr path
    __shared__ int cand_s[4][32];      // knn path

    const int blk = blockIdx.x;
    const int tid = threadIdx.x;

    if (blk < PREP_NB) {
        // ---------------- prep path ----------------
        int i = blk * 256 + tid;
        if (i < 4 * KT * 64) {
            int wv = i / (KT * 64);
            int r  = i - wv * (KT * 64);
            int t  = r >> 6, l = r & 63;
            int o  = (wv << 4) + (l & 15);
            int j  = (t << 5) + ((l >> 4) << 3);
            const float* s = cw + (size_t)o * (C2 * KSS) + j;
            uint4 v;
            v.x = pk2(s[0], s[1]);
            v.y = pk2(s[2], s[3]);
            v.z = pk2(s[4], s[5]);
            v.w = pk2(s[6], s[7]);
            aFrag[i] = v;
        }
        if (i < COUT * CIN) {
            int o = i >> 6, c = i & 63;
            mowT[c * COUT + o] = mw[o * CIN + c];
        }
        return;
    }

    if (blk < PREP_NB + TR_NB) {
        // ---------------- transpose path ----------------
        const int bt = blk - PREP_NB;      // b*32 + ntile
        const int b  = bt >> 5;
        const int n0 = (bt & 31) << 6;
        const int tn  = tid & 63;
        const int tc0 = tid >> 6;          // 0..3
#pragma unroll
        for (int r = 0; r < 16; ++r) {
            int c = (r << 2) + tc0;
            tile[c][tn] = f[((size_t)(b * CIN + c)) * NN + n0 + tn];
        }
        __syncthreads();
#pragma unroll
        for (int r = 0; r < 16; ++r) {
            int n = (r << 2) + tc0;
            ft[((size_t)b * NN + n0 + n) * CIN + tn] = tile[tn][n];
        }
        return;
    }

    // ---------------- KNN path ----------------
    const int w    = tid >> 6;
    const int lane = tid & 63;
    const int p    = (blk - PREP_NB - TR_NB) * 4 + w;
    const int b    = p >> 11;
    const int n    = p & (NN - 1);

    const float* xb0 = x + (size_t)(b * 3 + 0) * NN;
    const float* xb1 = x + (size_t)(b * 3 + 1) * NN;
    const float* xb2 = x + (size_t)(b * 3 + 2) * NN;

    const unsigned long long SENT = 0xFFFFFFFFFFFFFFFFull;
    const float qx = xb0[n], qy = xb1[n], qz = xb2[n];

    // ---- build: 2 independent top-4 chains (halved serial chain) ----
    unsigned long long a0 = SENT, a1 = SENT, a2 = SENT, a3 = SENT;
    unsigned long long e0 = SENT, e1 = SENT, e2 = SENT, e3 = SENT;
#pragma unroll
    for (int jj = 0; jj < 8; ++jj) {
        const int m0 = jj * 256 + lane * 4;
        const float4 vx = *(const float4*)&xb0[m0];
        const float4 vy = *(const float4*)&xb1[m0];
        const float4 vz = *(const float4*)&xb2[m0];
        const float d0 = d2f(vx.x, vy.x, vz.x, qx, qy, qz);
        const float d1 = d2f(vx.y, vy.y, vz.y, qx, qy, qz);
        const float d2 = d2f(vx.z, vy.z, vz.z, qx, qy, qz);
        const float d3 = d2f(vx.w, vy.w, vz.w, qx, qy, qz);
        unsigned long long pk0 =
            ((unsigned long long)__float_as_uint(d0) << 32) | (unsigned)(m0 + 0);
        unsigned long long pk1 =
            ((unsigned long long)__float_as_uint(d1) << 32) | (unsigned)(m0 + 1);
        unsigned long long pk2_ =
            ((unsigned long long)__float_as_uint(d2) << 32) | (unsigned)(m0 + 2);
        unsigned long long pk3 =
            ((unsigned long long)__float_as_uint(d3) << 32) | (unsigned)(m0 + 3);
        INS4(a0, a1, a2, a3, pk0);
        INS4(a0, a1, a2, a3, pk1);
        INS4(e0, e1, e2, e3, pk2_);
        INS4(e0, e1, e2, e3, pk3);
    }
    unsigned long long c0, c1, c2, c3;
    MERGE4(c0, c1, c2, c3, a0, a1, a2, a3, e0, e1, e2, e3);

    const unsigned dv0 = (unsigned)(c0 >> 32), dv1 = (unsigned)(c1 >> 32);
    const unsigned dv2 = (unsigned)(c2 >> 32), dv3 = (unsigned)(c3 >> 32);

    // ---- radix select: tau = 24th smallest d2bits over 256 cached keys ----
    unsigned pfx = 0u;
    for (int i = 30; i >= 0; --i) {      // bit31 of +float is always 0
        unsigned T = pfx | (1u << i);
        int cnt = (int)(dv0 < T) + (int)(dv1 < T) + (int)(dv2 < T) + (int)(dv3 < T);
        unsigned long long B0 = __ballot(cnt & 1);
        unsigned long long B1 = __ballot(cnt & 2);
        unsigned long long B2 = __ballot(cnt & 4);
        int tot = __popcll(B0) + 2 * __popcll(B1) + 4 * __popcll(B2);
        if (tot < NC) pfx = T;           // kth >= T -> set this bit
    }
    const unsigned tau = pfx;

    // ---- counts at tau; trigger decides fast vs fallback (wave-uniform) ----
    int cle = (int)(dv0 <= tau) + (int)(dv1 <= tau)
            + (int)(dv2 <= tau) + (int)(dv3 <= tau);
    unsigned long long L0 = __ballot(cle & 1);
    unsigned long long L1 = __ballot(cle & 2);
    unsigned long long L2 = __ballot(cle & 4);
    int tot_le = __popcll(L0) + 2 * __popcll(L1) + 4 * __popcll(L2);
    const bool trigger = (tot_le != NC) || (__ballot(cle == 4) != 0ull);

    int ci_cand = 0x7fffffff;
    if (!trigger) {
        // ---- fast path: prefix-compact the <=tau set (exactly 24 keys) ----
        unsigned long long below = (1ull << lane) - 1ull;
        int pre = __popcll(L0 & below) + 2 * __popcll(L1 & below);
        if (cle >= 1) cand_s[w][pre + 0] = (int)(unsigned)c0;
        if (cle >= 2) cand_s[w][pre + 1] = (int)(unsigned)c1;
        if (cle >= 3) cand_s[w][pre + 2] = (int)(unsigned)c2;
        if (lane < NC) ci_cand = cand_s[w][lane];   // wave-local, no barrier
    } else {
        // ---- fallback: sequential DPP extraction; rescan recomputes d2 ----
        unsigned killmask = 0u;
        unsigned long long mypk = SENT;
        for (int k = 0; k < NC; ++k) {
            unsigned myd  = (unsigned)(c0 >> 32);
            unsigned dmin = wave_min_u32(myd);
            unsigned idxc = (myd == dmin) ? (unsigned)c0 : 0xFFFFFFFFu;
            unsigned imin = wave_min_u32(idxc);
            unsigned long long bp = ((unsigned long long)dmin << 32) | imin;
            if (lane == k) mypk = bp;
            if (c0 == bp) {                       // unique owner lane
                unsigned mi = (unsigned)(bp & 0xFFFFFFFFull);
                killmask |= 1u << (((mi >> 8) << 2) | (mi & 3));
                c0 = c1; c1 = c2; c2 = c3; c3 = SENT;
                if (c0 == SENT) {                 // rare rescan (recompute)
                    for (int jj = 0; jj < 8; ++jj) {
                        const int m0 = jj * 256 + lane * 4;
                        const float4 vx = *(const float4*)&xb0[m0];
                        const float4 vy = *(const float4*)&xb1[m0];
                        const float4 vz = *(const float4*)&xb2[m0];
                        const float dd4[4] = { d2f(vx.x, vy.x, vz.x, qx, qy, qz),
                                               d2f(vx.y, vy.y, vz.y, qx, qy, qz),
                                               d2f(vx.z, vy.z, vz.z, qx, qy, qz),
                                               d2f(vx.w, vy.w, vz.w, qx, qy, qz) };
#pragma unroll
                        for (int e = 0; e < 4; ++e) {
                            if (killmask & (1u << ((jj << 2) | e))) continue;
                            unsigned long long pk =
                                ((unsigned long long)__float_as_uint(dd4[e]) << 32)
                                | (unsigned)(m0 + e);
                            INS4(c0, c1, c2, c3, pk);
                        }
                    }
                }
            }
        }
        if (lane < NC) ci_cand = (int)(mypk & 0xFFFFFFFFull);
    }

    // ---- double-precision refine + full bitonic sort (order-independent) --
    double dd = 1e300;
    int ci = 0x7fffffff;
    if (lane < NC) {
        ci = ci_cand;
        double dx = (double)xb0[ci] - (double)qx;
        double dy = (double)xb1[ci] - (double)qy;
        double dz = (double)xb2[ci] - (double)qz;
        dd = dx * dx + dy * dy + dz * dz;
    }
    unsigned long long db = __double_as_longlong(dd);
#pragma unroll
    for (int size = 2; size <= 32; size <<= 1) {
#pragma unroll
        for (int stride = size >> 1; stride > 0; stride >>= 1) {
            unsigned long long odb = __shfl_xor(db, stride);
            int oci = __shfl_xor(ci, stride);
            bool up = ((lane & size) == 0);
            bool takemin = (((lane & stride) == 0) == up);
            bool oless = (odb < db) || (odb == db && oci < ci);
            if (takemin == oless) { db = odb; ci = oci; }
        }
    }
    if (lane < KK) nid[(size_t)p * KK + lane] = ci;
}

// ---------------------------------------------------------------------------
// FUSED kernel — EXACT r12/r17 best-measured body at (256,3): 111 µs,
// VGPR 72, no spill. r18's BN-stat fusion reverted (+23 µs).
// ---------------------------------------------------------------------------
__global__ __launch_bounds__(256, 3) void point_kernel(
    const float* __restrict__ x,
    const float* __restrict__ featT,
    const float* __restrict__ kern,
    const float* __restrict__ pad,
    const float* __restrict__ mlp_w,
    const float* __restrict__ mlp_b,
    const uint4* __restrict__ aFrag,
    const float* __restrict__ conv_b,
    const float* __restrict__ mowT,
    const float* __restrict__ mob,
    const int* __restrict__ nid,
    float* __restrict__ out)
{
    __shared__ __align__(16) _Float16 agg_h[PPB][AGG_LD];    // 20608 B
    __shared__ __align__(16) float u_s[PPB * KK * KSS];      // 6400 B (perm|red2)
    __shared__ float xr_s[PPB][KK][3];
    __shared__ float xd_s[PPB][KK];
    __shared__ float xrep_s[PPB][3];
    __shared__ float colden_s[PPB][KSS];
    __shared__ float fcol_s[PPB][CIN];
    __shared__ int   nid_s[PPB][KK];

    float (*perm_s)[KK][KSS] = (float (*)[KK][KSS])u_s;
    float (*red2)[COUT]      = (float (*)[COUT])u_s;   // aliased post-barrier1

    const int tid  = threadIdx.x;
    const int w    = tid >> 6;
    const int lane = tid & 63;
    const int p    = blockIdx.x * PPB + w;
    const int b    = p >> 11;
    const int n    = p & (NN - 1);

    const float* xb0 = x + (size_t)(b * 3 + 0) * NN;
    const float* xb1 = x + (size_t)(b * 3 + 1) * NN;
    const float* xb2 = x + (size_t)(b * 3 + 2) * NN;

    // ---- neighbor ids from the KNN kernel (wave-local LDS stage) ----
    if (lane < KK) nid_s[w][lane] = nid[(size_t)p * KK + lane];

    // ======= per-point pipeline: all wave-local, NO barriers needed =======
    fcol_s[w][lane] = featT[((size_t)b * NN + n) * CIN + lane];

    if (lane == 0) {
        int m0 = nid_s[w][0];
        xrep_s[w][0] = xb0[m0]; xrep_s[w][1] = xb1[m0]; xrep_s[w][2] = xb2[m0];
    }
    if (lane < KK) {
        int m = nid_s[w][lane];
        float rx = xb0[m] - xrep_s[w][0];
        float ry = xb1[m] - xrep_s[w][1];
        float rz = xb2[m] - xrep_s[w][2];
        xr_s[w][lane][0] = rx; xr_s[w][lane][1] = ry; xr_s[w][lane][2] = rz;
        xd_s[w][lane] = sqrtf(rx * rx + ry * ry + rz * rz + 1e-12f);
    }

    // ---- perm: relu -> colnorm -> square -> colnorm -> >0.1 (wave-local) --
    for (int e = lane; e < KK * KSS; e += 64) {
        int k = e / KSS, m = e % KSS;
        float v = xr_s[w][k][0] * kern[0 * KSS + m]
                + xr_s[w][k][1] * kern[1 * KSS + m]
                + xr_s[w][k][2] * kern[2 * KSS + m]
                + pad[k * KSS + m];
        perm_s[w][k][m] = v > 0.0f ? v : 0.0f;
    }
    if (lane < KSS) {
        float s = 0.0f;
        for (int k = 0; k < KK; ++k) s += perm_s[w][k][lane];
        colden_s[w][lane] = s + 1e-6f;
    }
    for (int e = lane; e < KK * KSS; e += 64) {
        int k = e / KSS, m = e % KSS;
        float v = perm_s[w][k][m] / colden_s[w][m];
        perm_s[w][k][m] = v * v;
    }
    if (lane < KSS) {
        float s = 0.0f;
        for (int k = 0; k < KK; ++k) s += perm_s[w][k][lane];
        colden_s[w][lane] = s + 1e-6f;
    }
    for (int e = lane; e < KK * KSS; e += 64) {
        int k = e / KSS, m = e % KSS;
        float v = perm_s[w][k][m] / colden_s[w][m];
        perm_s[w][k][m] = v > 0.1f ? v : 0.0f;
    }

    // ---- feats in registers (coalesced gathers from featT) ----
    float fg[KK], fm[KK];
#pragma unroll
    for (int k = 0; k < KK; ++k)
        fg[k] = featT[((size_t)b * NN + nid_s[w][k]) * CIN + lane];
    {
        float w0 = mlp_w[lane * 7 + 0], w1 = mlp_w[lane * 7 + 1];
        float w2 = mlp_w[lane * 7 + 2], w3 = mlp_w[lane * 7 + 3];
        float w4 = mlp_w[lane * 7 + 4], w5 = mlp_w[lane * 7 + 5];
        float w6 = mlp_w[lane * 7 + 6];
        float bias = mlp_b[lane];
#pragma unroll
        for (int k = 0; k < KK; ++k) {
            fm[k] = xrep_s[w][0] * w0 + xrep_s[w][1] * w1 + xrep_s[w][2] * w2
                  + xr_s[w][k][0] * w3 + xr_s[w][k][1] * w4 + xr_s[w][k][2] * w5
                  + xd_s[w][k] * w6 + bias;
        }
    }

    // ---- agg rows c=lane, c=64+lane; float4 perm reads (broadcast, free) --
#pragma unroll
    for (int m4 = 0; m4 < KSS / 4; ++m4) {
        float sx = 0.f, sy = 0.f, sz = 0.f, sw = 0.f;
        float tx = 0.f, ty = 0.f, tz = 0.f, tw = 0.f;
#pragma unroll
        for (int k = 0; k < KK; ++k) {
            const float4 pv = *(const float4*)&perm_s[w][k][m4 * 4];
            const float a = fg[k], c = fm[k];
            sx += a * pv.x; sy += a * pv.y; sz += a * pv.z; sw += a * pv.w;
            tx += c * pv.x; ty += c * pv.y; tz += c * pv.z; tw += c * pv.w;
        }
        const int mb = m4 * 4;
        agg_h[w][lane * KSS + mb + 0]         = (_Float16)sx;
        agg_h[w][lane * KSS + mb + 1]         = (_Float16)sy;
        agg_h[w][lane * KSS + mb + 2]         = (_Float16)sz;
        agg_h[w][lane * KSS + mb + 3]         = (_Float16)sw;
        agg_h[w][(CIN + lane) * KSS + mb + 0] = (_Float16)tx;
        agg_h[w][(CIN + lane) * KSS + mb + 1] = (_Float16)ty;
        agg_h[w][(CIN + lane) * KSS + mb + 2] = (_Float16)tz;
        agg_h[w][(CIN + lane) * KSS + mb + 3] = (_Float16)tw;
    }
    __syncthreads();   // BARRIER 1: cross-wave agg_h; perm_s -> red2 handoff

    // ---- cooperative conv on the MATRIX pipe: wave w = outputs 16w..16w+15
    {
        f32x4 acc0 = {0.f, 0.f, 0.f, 0.f};
        f32x4 acc1 = {0.f, 0.f, 0.f, 0.f};
        const uint4* ap = aFrag + (size_t)(w * KT) * 64 + lane;
        const _Float16* bp = &agg_h[lane & 3][(lane >> 4) * 8];
#pragma unroll 4
        for (int t = 0; t < KT; t += 2) {
            uint4 av0 = ap[(size_t)t * 64];
            uint4 av1 = ap[(size_t)(t + 1) * 64];
            f16x8 b0 = *(const f16x8*)(bp + t * 32);
            f16x8 b1 = *(const f16x8*)(bp + (t + 1) * 32);
            acc0 = __builtin_amdgcn_mfma_f32_16x16x32_f16(
                       __builtin_bit_cast(f16x8, av0), b0, acc0, 0, 0, 0);
            acc1 = __builtin_amdgcn_mfma_f32_16x16x32_f16(
                       __builtin_bit_cast(f16x8, av1), b1, acc1, 0, 0, 0);
        }
        acc0 += acc1;
        if ((lane & 15) < 4) {
            const int p2 = lane & 15;
            const int ob = (w << 4) + ((lane >> 4) << 2);
            *(f32x4*)&red2[p2][ob] = acc0;
        }
    }
    __syncthreads();   // BARRIER 2: cross-wave red2

    // ---- wave w finalizes point w ----
    {
        float acc = conv_b[lane] + red2[w][lane];
        for (int c = 0; c < CIN; ++c)
            acc += fcol_s[w][c] * mowT[c * COUT + lane];
        acc += mob[lane];
        out[(size_t)(b * COUT + lane) * NN + n] = acc;
    }
}

// ---------------------------------------------------------------------------
// BatchNorm split: 512-block reduce into partials, 512-block apply.
// ---------------------------------------------------------------------------
__global__ __launch_bounds__(256) void bn_reduce(
    const float* __restrict__ out, float* __restrict__ part)
{
    const int o = blockIdx.x >> 3;     // channel
    const int s = blockIdx.x & 7;      // batch index
    const float* src = out + (size_t)(s * COUT + o) * NN;
    float a = 0.f, q = 0.f;
    for (int i = threadIdx.x; i < NN; i += 256) {
        float v = src[i];
        a += v; q += v * v;
    }
    __shared__ float s1[256], s2[256];
    s1[threadIdx.x] = a; s2[threadIdx.x] = q;
    __syncthreads();
    for (int st = 128; st > 0; st >>= 1) {
        if (threadIdx.x < st) {
            s1[threadIdx.x] += s1[threadIdx.x + st];
            s2[threadIdx.x] += s2[threadIdx.x + st];
        }
        __syncthreads();
    }
    if (threadIdx.x == 0) {
        part[(o * 8 + s) * 2 + 0] = s1[0];
        part[(o * 8 + s) * 2 + 1] = s2[0];
    }
}

__global__ __launch_bounds__(256) void bn_apply(
    float* __restrict__ out, const float* __restrict__ part,
    const float* __restrict__ gamma, const float* __restrict__ beta)
{
    const int o = blockIdx.x >> 3;
    const int s = blockIdx.x & 7;
    float a = 0.f, q = 0.f;
#pragma unroll
    for (int t = 0; t < 8; ++t) {
        a += part[(o * 8 + t) * 2 + 0];
        q += part[(o * 8 + t) * 2 + 1];
    }
    const float M = (float)(BB * NN);
    const float mean = a / M;
    float var = q / M - mean * mean;
    if (var < 0.f) var = 0.f;
    const float inv = 1.0f / sqrtf(var + 1e-5f);
    const float g = gamma[o] * inv, be = beta[o];
    float* dst = out + (size_t)(s * COUT + o) * NN;
    for (int i = threadIdx.x; i < NN; i += 256) {
        dst[i] = (dst[i] - mean) * g + be;
    }
}

// ---------------------------------------------------------------------------
extern "C" void kernel_launch(void* const* d_in, const int* in_sizes, int n_in,
                              void* d_out, int out_size, void* d_ws, size_t ws_size,
                              hipStream_t stream)
{
    const float* x       = (const float*)d_in[0];
    const float* feature = (const float*)d_in[1];
    const float* kern    = (const float*)d_in[2];
    const float* pad     = (const float*)d_in[3];
    const float* mlp_w   = (const float*)d_in[4];
    const float* mlp_b   = (const float*)d_in[5];
    const float* conv_w  = (const float*)d_in[6];
    const float* conv_b  = (const float*)d_in[7];
    const float* mow     = (const float*)d_in[8];
    const float* mob     = (const float*)d_in[9];
    const float* gamma   = (const float*)d_in[10];
    const float* beta    = (const float*)d_in[11];

    char* wsp = (char*)d_ws;
    uint4* aFrag = (uint4*)wsp;                        // 327680 B
    float* mowT  = (float*)(wsp + 327680);             //  16384 B
    float* part  = (float*)(wsp + 327680 + 16384);     //   4096 B
    int*   nid   = (int*)(wsp + 327680 + 16384 + 4096);// 1310720 B
    float* featT = (float*)(wsp + 327680 + 16384 + 4096 + 1310720); // 4 MB

    float* out = (float*)d_out;

    front_kernel<<<PREP_NB + TR_NB + KNN_NB, 256, 0, stream>>>(
        conv_w, mow, aFrag, mowT, feature, featT, x, nid);
    point_kernel<<<BB * NN / PPB, 256, 0, stream>>>(x, featT, kern, pad,
                                                    mlp_w, mlp_b, aFrag, conv_b,
                                                    mowT, mob, nid, out);
    bn_reduce<<<512, 256, 0, stream>>>(out, part);
    bn_apply<<<512, 256, 0, stream>>>(out, part, gamma, beta);
}